// Round 3
// baseline (7227.912 us; speedup 1.0000x reference)
//
#include <hip/hip_runtime.h>

#define NUM_USERS 200000
#define NUM_ITEMS 100000
#define NN (NUM_USERS + NUM_ITEMS)   // 300000
#define D 32
#define NE 9600000
#define TOTAL (NN * D)               // 9,600,000 floats

#define RPB 128                      // rows per bucket
#define NB ((NN + RPB - 1) / RPB)    // 2344 buckets (2344*128 = 300032)

// ---------------------------------------------------------------------------
// init: x0 = concat(user_w, item_w); acc = x0. float4-vectorized.
__global__ __launch_bounds__(256) void init_x_acc(
    const float4* __restrict__ user_w, const float4* __restrict__ item_w,
    float4* __restrict__ x, float4* __restrict__ acc) {
    int i = blockIdx.x * 256 + threadIdx.x;          // float4 index
    const int total4 = TOTAL / 4;                    // 2,400,000
    const int ub4 = (NUM_USERS * D) / 4;             // 1,600,000
    if (i < total4) {
        float4 v = (i < ub4) ? user_w[i] : item_w[i - ub4];
        x[i] = v;
        acc[i] = v;
    }
}

// ---------------------------------------------------------------------------
// Bucket histogram: 2344 counters (must be pre-zeroed).
__global__ __launch_bounds__(256) void bucket_hist(
    const int* __restrict__ rows, int* __restrict__ counts) {
    int e = blockIdx.x * 256 + threadIdx.x;
    if (e < NE) atomicAdd(&counts[rows[e] >> 7], 1);
}

// ---------------------------------------------------------------------------
// Exclusive scan of 2344 bucket counts -> bstart[NB+1], fill[NB].
// Single block of 1024 threads, chunk-per-thread + LDS Hillis-Steele.
__global__ __launch_bounds__(1024) void scan_buckets(
    const int* __restrict__ counts, int* __restrict__ bstart,
    int* __restrict__ fill) {
    __shared__ int lds[1024];
    const int T = 1024;
    const int CH = (NB + T - 1) / T;                 // 3
    int t = threadIdx.x;
    int begin = t * CH;
    int end = begin + CH; if (end > NB) end = NB;
    int s = 0;
    for (int i = begin; i < end; ++i) s += counts[i];
    lds[t] = s;
    __syncthreads();
    for (int off = 1; off < T; off <<= 1) {
        int v = (t >= off) ? lds[t - off] : 0;
        __syncthreads();
        lds[t] += v;
        __syncthreads();
    }
    int run = lds[t] - s;                            // exclusive prefix
    for (int i = begin; i < end; ++i) {
        bstart[i] = run;
        fill[i] = run;
        run += counts[i];
    }
    if (t == T - 1) bstart[NB] = run;                // == NE
}

// ---------------------------------------------------------------------------
// Bucket scatter: append (col | row_local<<19, val) into the bucket's region.
// Appends to a bucket land in consecutive slots -> dense 64B-line writes.
__global__ __launch_bounds__(256) void bucket_scatter(
    const int* __restrict__ rows, const int* __restrict__ cols,
    const float* __restrict__ vals, int* __restrict__ fill,
    int2* __restrict__ colval) {
    int e = blockIdx.x * 256 + threadIdx.x;
    if (e < NE) {
        int r = rows[e];
        int b = r >> 7;
        int p = atomicAdd(&fill[b], 1);
        int2 cv;
        cv.x = cols[e] | ((r & 127) << 19);          // col:19 bits, row_local:7 bits
        cv.y = __float_as_int(vals[e]);
        colval[p] = cv;
    }
}

// ---------------------------------------------------------------------------
// SpMM, one block per 128-row bucket. LDS accumulator 128x32 fp32 = 16 KB.
// 8 edge-groups of 32 lanes (lane = feature). Edges unsorted within bucket;
// LDS fp32 atomicAdd (ds_add_f32), lane-consecutive -> bank-conflict-free.
// Epilogue: coalesced float4 write of y, fused acc += y (and *0.25 if LAST).
template <bool LAST>
__global__ __launch_bounds__(256) void spmm_bucket(
    const int* __restrict__ bstart, const int2* __restrict__ colval,
    const float* __restrict__ x, float* __restrict__ y,
    float* __restrict__ acc) {
    __shared__ float yl[RPB * D];                    // 16 KB
    float4* yl4 = (float4*)yl;
    for (int j = threadIdx.x; j < RPB * D / 4; j += 256)
        yl4[j] = make_float4(0.f, 0.f, 0.f, 0.f);
    __syncthreads();

    int b = blockIdx.x;
    int s = bstart[b];
    int e = bstart[b + 1];
    int lane = threadIdx.x & 31;
    int g = threadIdx.x >> 5;                        // 0..7

    int i = s + g * 2;
    for (; i + 1 < e; i += 16) {                     // unroll-2: 2 gathers in flight
        int2 cv0 = colval[i];
        int2 cv1 = colval[i + 1];
        float p0 = __int_as_float(cv0.y) * x[(cv0.x & 0x7FFFF) * D + lane];
        float p1 = __int_as_float(cv1.y) * x[(cv1.x & 0x7FFFF) * D + lane];
        atomicAdd(&yl[(cv0.x >> 19) * D + lane], p0);
        atomicAdd(&yl[(cv1.x >> 19) * D + lane], p1);
    }
    if (i < e) {
        int2 cv = colval[i];
        float p = __int_as_float(cv.y) * x[(cv.x & 0x7FFFF) * D + lane];
        atomicAdd(&yl[(cv.x >> 19) * D + lane], p);
    }
    __syncthreads();

    int rowbase = b * RPB;
    float4* y4 = (float4*)y;
    float4* a4 = (float4*)acc;
    for (int j = threadIdx.x; j < RPB * D / 4; j += 256) {
        int rl = j >> 3;                             // 8 float4 per row
        if (rowbase + rl < NN) {
            float4 v = yl4[j];
            size_t o = (size_t)b * (RPB * D / 4) + j;
            float4 a = a4[o];
            a.x += v.x; a.y += v.y; a.z += v.z; a.w += v.w;
            if (LAST) { a.x *= 0.25f; a.y *= 0.25f; a.z *= 0.25f; a.w *= 0.25f; }
            y4[o] = v;
            a4[o] = a;
        }
    }
}

extern "C" void kernel_launch(void* const* d_in, const int* in_sizes, int n_in,
                              void* d_out, int out_size, void* d_ws, size_t ws_size,
                              hipStream_t stream) {
    const int*   rows   = (const int*)d_in[0];
    const int*   cols   = (const int*)d_in[1];
    const float* vals   = (const float*)d_in[2];
    const float* user_w = (const float*)d_in[3];
    const float* item_w = (const float*)d_in[4];

    float* acc = (float*)d_out;                      // N*D fp32, == output layout

    // ws: x (38.4MB) | y (38.4MB) | colval (76.8MB) | counts | bstart | fill
    float* x = (float*)d_ws;
    float* y = x + (size_t)TOTAL;
    int2*  colval = (int2*)(y + (size_t)TOTAL);
    int*   counts = (int*)(colval + (size_t)NE);
    int*   bstart = counts + NB;
    int*   fill   = bstart + (NB + 1);

    const int vec_blocks  = (TOTAL / 4 + 255) / 256; // 9375
    const int edge_blocks = (NE + 255) / 256;        // 37500

    init_x_acc<<<vec_blocks, 256, 0, stream>>>(
        (const float4*)user_w, (const float4*)item_w, (float4*)x, (float4*)acc);

    hipMemsetAsync(counts, 0, (size_t)NB * sizeof(int), stream);
    bucket_hist<<<edge_blocks, 256, 0, stream>>>(rows, counts);
    scan_buckets<<<1, 1024, 0, stream>>>(counts, bstart, fill);
    bucket_scatter<<<edge_blocks, 256, 0, stream>>>(rows, cols, vals, fill, colval);

    spmm_bucket<false><<<NB, 256, 0, stream>>>(bstart, colval, x, y, acc);
    spmm_bucket<false><<<NB, 256, 0, stream>>>(bstart, colval, y, x, acc);
    spmm_bucket<true ><<<NB, 256, 0, stream>>>(bstart, colval, x, y, acc);
}

// Round 4
// 2564.604 us; speedup vs baseline: 2.8183x; 2.8183x over previous
//
#include <hip/hip_runtime.h>

#define NUM_USERS 200000
#define NUM_ITEMS 100000
#define NN (NUM_USERS + NUM_ITEMS)   // 300000
#define D 32
#define NE 9600000
#define TOTAL (NN * D)               // 9,600,000 floats

// ---------------------------------------------------------------------------
// init: x0 = concat(user_w, item_w); acc = x0. float4-vectorized.
__global__ __launch_bounds__(256) void init_x_acc(
    const float4* __restrict__ user_w, const float4* __restrict__ item_w,
    float4* __restrict__ x, float4* __restrict__ acc) {
    int i = blockIdx.x * 256 + threadIdx.x;          // float4 index
    const int total4 = TOTAL / 4;                    // 2,400,000
    const int ub4 = (NUM_USERS * D) / 4;             // 1,600,000
    if (i < total4) {
        float4 v = (i < ub4) ? user_w[i] : item_w[i - ub4];
        x[i] = v;
        acc[i] = v;
    }
}

// ---------------------------------------------------------------------------
// CSR build step 1: degree histogram over 300K rows (counts pre-zeroed).
__global__ __launch_bounds__(256) void hist_kernel(
    const int* __restrict__ rows, int* __restrict__ counts) {
    int e = blockIdx.x * 256 + threadIdx.x;
    if (e < NE) atomicAdd(&counts[rows[e]], 1);
}

// ---------------------------------------------------------------------------
// CSR build step 2: exclusive scan counts -> row_start[NN+1], fill_pos[NN].
// Single 1024-thread block, chunk-per-thread + LDS Hillis-Steele.
__global__ __launch_bounds__(1024) void scan_kernel(
    const int* __restrict__ counts, int* __restrict__ row_start,
    int* __restrict__ fill_pos) {
    __shared__ int lds[1024];
    const int T = 1024;
    const int CH = (NN + T - 1) / T;                 // 293
    int t = threadIdx.x;
    int begin = t * CH;
    int end = begin + CH; if (end > NN) end = NN;
    int s = 0;
    for (int i = begin; i < end; ++i) s += counts[i];
    lds[t] = s;
    __syncthreads();
    for (int off = 1; off < T; off <<= 1) {
        int v = (t >= off) ? lds[t - off] : 0;
        __syncthreads();
        lds[t] += v;
        __syncthreads();
    }
    int run = lds[t] - s;                            // exclusive prefix of chunk
    for (int i = begin; i < end; ++i) {
        row_start[i] = run;
        fill_pos[i] = run;
        run += counts[i];
    }
    if (t == T - 1) row_start[NN] = run;             // == NE
}

// ---------------------------------------------------------------------------
// CSR build step 3: scatter (col,val) into row-grouped storage.
// 4 edges per thread: coalesced int4/float4 input loads, 4 independent
// atomicAdd round-trips in flight, then 4 stores.
__global__ __launch_bounds__(256) void scatter_kernel(
    const int4* __restrict__ rows4, const int4* __restrict__ cols4,
    const float4* __restrict__ vals4, int* __restrict__ fill_pos,
    int2* __restrict__ colval) {
    int t = blockIdx.x * 256 + threadIdx.x;          // quad index
    if (t < NE / 4) {
        int4   r = rows4[t];
        int4   c = cols4[t];
        float4 v = vals4[t];
        int p0 = atomicAdd(&fill_pos[r.x], 1);
        int p1 = atomicAdd(&fill_pos[r.y], 1);
        int p2 = atomicAdd(&fill_pos[r.z], 1);
        int p3 = atomicAdd(&fill_pos[r.w], 1);
        int2 cv;
        cv.x = c.x; cv.y = __float_as_int(v.x); colval[p0] = cv;
        cv.x = c.y; cv.y = __float_as_int(v.y); colval[p1] = cv;
        cv.x = c.z; cv.y = __float_as_int(v.z); colval[p2] = cv;
        cv.x = c.w; cv.y = __float_as_int(v.w); colval[p3] = cv;
    }
}

// ---------------------------------------------------------------------------
// Atomic-free SpMM: one 32-lane half-wave per row (lane = feature d).
// Unroll-4: 4 independent 128B gathers in flight per half-wave.
// Fused: y[row] store + acc += y (and *0.25 on the last layer).
template <bool LAST>
__global__ __launch_bounds__(256) void spmm_csr(
    const int* __restrict__ row_start, const int2* __restrict__ colval,
    const float* __restrict__ x, float* __restrict__ y,
    float* __restrict__ acc) {
    int lane = threadIdx.x & 31;
    int row = blockIdx.x * 8 + (threadIdx.x >> 5);   // 8 rows per 256-thread block
    if (row >= NN) return;
    int s = row_start[row];
    int e = row_start[row + 1];
    float s0 = 0.f, s1 = 0.f, s2 = 0.f, s3 = 0.f;
    int i = s;
    for (; i + 3 < e; i += 4) {
        int2 a = colval[i];
        int2 b = colval[i + 1];
        int2 c = colval[i + 2];
        int2 d = colval[i + 3];
        s0 += __int_as_float(a.y) * x[a.x * D + lane];
        s1 += __int_as_float(b.y) * x[b.x * D + lane];
        s2 += __int_as_float(c.y) * x[c.x * D + lane];
        s3 += __int_as_float(d.y) * x[d.x * D + lane];
    }
    for (; i < e; ++i) {
        int2 a = colval[i];
        s0 += __int_as_float(a.y) * x[a.x * D + lane];
    }
    float sum = (s0 + s1) + (s2 + s3);
    int idx = row * D + lane;
    y[idx] = sum;
    float a = acc[idx] + sum;
    acc[idx] = LAST ? a * 0.25f : a;
}

extern "C" void kernel_launch(void* const* d_in, const int* in_sizes, int n_in,
                              void* d_out, int out_size, void* d_ws, size_t ws_size,
                              hipStream_t stream) {
    const int*   rows   = (const int*)d_in[0];
    const int*   cols   = (const int*)d_in[1];
    const float* vals   = (const float*)d_in[2];
    const float* user_w = (const float*)d_in[3];
    const float* item_w = (const float*)d_in[4];

    float* acc = (float*)d_out;                      // N*D fp32, == output layout

    // ws: x (38.4MB) | y (38.4MB) | colval (76.8MB) | counts | row_start | fill_pos
    float* x = (float*)d_ws;
    float* y = x + (size_t)TOTAL;
    int2*  colval = (int2*)(y + (size_t)TOTAL);
    int*   counts = (int*)(colval + (size_t)NE);
    int*   row_start = counts + NN;
    int*   fill_pos = row_start + (NN + 1);

    const int vec_blocks  = (TOTAL / 4 + 255) / 256; // 9375
    const int edge_blocks = (NE + 255) / 256;        // 37500
    const int quad_blocks = (NE / 4 + 255) / 256;    // 9375
    const int row_blocks  = (NN + 7) / 8;            // 37500

    init_x_acc<<<vec_blocks, 256, 0, stream>>>(
        (const float4*)user_w, (const float4*)item_w, (float4*)x, (float4*)acc);

    hipMemsetAsync(counts, 0, (size_t)NN * sizeof(int), stream);
    hist_kernel<<<edge_blocks, 256, 0, stream>>>(rows, counts);
    scan_kernel<<<1, 1024, 0, stream>>>(counts, row_start, fill_pos);
    scatter_kernel<<<quad_blocks, 256, 0, stream>>>(
        (const int4*)rows, (const int4*)cols, (const float4*)vals, fill_pos, colval);

    spmm_csr<false><<<row_blocks, 256, 0, stream>>>(row_start, colval, x, y, acc);
    spmm_csr<false><<<row_blocks, 256, 0, stream>>>(row_start, colval, y, x, acc);
    spmm_csr<true ><<<row_blocks, 256, 0, stream>>>(row_start, colval, x, y, acc);
}

// Round 5
// 1980.600 us; speedup vs baseline: 3.6494x; 1.2949x over previous
//
#include <hip/hip_runtime.h>

#define NUM_USERS 200000
#define NUM_ITEMS 100000
#define NN (NUM_USERS + NUM_ITEMS)   // 300000
#define D 32
#define NE 9600000
#define TOTAL (NN * D)               // 9,600,000 floats

#define RPB2 128                     // rows per fine bucket
#define B2 ((NN + RPB2 - 1) / RPB2)  // 2344 buckets; region == CSR slice of 128 rows
#define CAP 5120                     // LDS stage capacity (mean 4096, sigma ~64)

#define TPB_A 1024                   // partition block size
#define EPT 16                       // edges per thread in partition
#define EPB_A (TPB_A * EPT)          // 16384 edges per block

// ---------------------------------------------------------------------------
// init: x0 = concat(user_w, item_w); acc = x0. Runs AFTER the CSR build
// because the build's temp array aliases the x|y workspace.
__global__ __launch_bounds__(256) void init_x_acc(
    const float4* __restrict__ user_w, const float4* __restrict__ item_w,
    float4* __restrict__ x, float4* __restrict__ acc) {
    int i = blockIdx.x * 256 + threadIdx.x;
    const int total4 = TOTAL / 4;
    const int ub4 = (NUM_USERS * D) / 4;
    if (i < total4) {
        float4 v = (i < ub4) ? user_w[i] : item_w[i - ub4];
        x[i] = v;
        acc[i] = v;
    }
}

// ---------------------------------------------------------------------------
// Degree histogram, int4-vectorized (counts pre-zeroed).
__global__ __launch_bounds__(256) void hist_kernel(
    const int4* __restrict__ rows4, int* __restrict__ counts) {
    int t = blockIdx.x * 256 + threadIdx.x;
    if (t < NE / 4) {
        int4 r = rows4[t];
        atomicAdd(&counts[r.x], 1);
        atomicAdd(&counts[r.y], 1);
        atomicAdd(&counts[r.z], 1);
        atomicAdd(&counts[r.w], 1);
    }
}

// ---------------------------------------------------------------------------
// Exclusive scan counts -> row_start[NN+1]; also gfill[NN] (fallback fill
// counters, init = row_start). Single 1024-thread block.
__global__ __launch_bounds__(1024) void scan_kernel(
    const int* __restrict__ counts, int* __restrict__ row_start,
    int* __restrict__ gfill) {
    __shared__ int lds[1024];
    const int T = 1024;
    const int CH = (NN + T - 1) / T;                 // 293
    int t = threadIdx.x;
    int begin = t * CH;
    int end = begin + CH; if (end > NN) end = NN;
    int s = 0;
    for (int i = begin; i < end; ++i) s += counts[i];
    lds[t] = s;
    __syncthreads();
    for (int off = 1; off < T; off <<= 1) {
        int v = (t >= off) ? lds[t - off] : 0;
        __syncthreads();
        lds[t] += v;
        __syncthreads();
    }
    int run = lds[t] - s;
    for (int i = begin; i < end; ++i) {
        row_start[i] = run;
        gfill[i] = run;
        run += counts[i];
    }
    if (t == T - 1) row_start[NN] = run;             // == NE
}

// ---------------------------------------------------------------------------
// Bucket fill counters: bfill[b] = row_start[b*128] (bucket region start).
__global__ __launch_bounds__(256) void bucket_starts(
    const int* __restrict__ row_start, int* __restrict__ bfill) {
    int b = blockIdx.x * 256 + threadIdx.x;
    if (b < B2) bfill[b] = row_start[b * RPB2];
}

// ---------------------------------------------------------------------------
// Pass A: block-privatized counting-split of edges into the 2344 bucket
// regions of temp. Per block: LDS histogram -> per-edge rank; one global
// atomicAdd per touched bucket reserves a contiguous run; phase-2 reload
// writes (row_local<<19|col, val) at base+rank — dense ~56B runs per CU.
__global__ __launch_bounds__(TPB_A) void partition_edges(
    const int4* __restrict__ rows4, const int4* __restrict__ cols4,
    const float4* __restrict__ vals4, int* __restrict__ bfill,
    int2* __restrict__ temp) {
    __shared__ int hist[B2];                         // 9376 B
    int tid = threadIdx.x;
    for (int i = tid; i < B2; i += TPB_A) hist[i] = 0;
    __syncthreads();

    int base4 = blockIdx.x * (EPB_A / 4);
    int brank[EPT];                                  // (bucket<<16)|rank per edge

    #pragma unroll
    for (int k = 0; k < EPT / 4; ++k) {
        int i4 = base4 + k * TPB_A + tid;
        if (i4 < NE / 4) {
            int4 r = rows4[i4];
            int b0 = r.x >> 7, b1 = r.y >> 7, b2 = r.z >> 7, b3 = r.w >> 7;
            brank[k * 4 + 0] = (b0 << 16) | atomicAdd(&hist[b0], 1);
            brank[k * 4 + 1] = (b1 << 16) | atomicAdd(&hist[b1], 1);
            brank[k * 4 + 2] = (b2 << 16) | atomicAdd(&hist[b2], 1);
            brank[k * 4 + 3] = (b3 << 16) | atomicAdd(&hist[b3], 1);
        }
    }
    __syncthreads();
    for (int b = tid; b < B2; b += TPB_A) {          // reserve runs
        int c = hist[b];
        if (c) hist[b] = atomicAdd(&bfill[b], c);    // hist now holds base
    }
    __syncthreads();

    #pragma unroll
    for (int k = 0; k < EPT / 4; ++k) {
        int i4 = base4 + k * TPB_A + tid;
        if (i4 < NE / 4) {
            int4 r = rows4[i4];
            int4 c = cols4[i4];
            float4 v = vals4[i4];
            int br, pos; int2 cv;
            br = brank[k * 4 + 0]; pos = hist[br >> 16] + (br & 0xFFFF);
            cv.x = ((r.x & 127) << 19) | c.x; cv.y = __float_as_int(v.x); temp[pos] = cv;
            br = brank[k * 4 + 1]; pos = hist[br >> 16] + (br & 0xFFFF);
            cv.x = ((r.y & 127) << 19) | c.y; cv.y = __float_as_int(v.y); temp[pos] = cv;
            br = brank[k * 4 + 2]; pos = hist[br >> 16] + (br & 0xFFFF);
            cv.x = ((r.z & 127) << 19) | c.z; cv.y = __float_as_int(v.z); temp[pos] = cv;
            br = brank[k * 4 + 3]; pos = hist[br >> 16] + (br & 0xFFFF);
            cv.x = ((r.w & 127) << 19) | c.w; cv.y = __float_as_int(v.w); temp[pos] = cv;
        }
    }
}

// ---------------------------------------------------------------------------
// Pass B: exact within-bucket counting sort through LDS. One block per
// bucket: contiguous read of temp region, LDS int-atomic ranks, staged
// (col,val) in LDS, fully-coalesced flush to final colval. Fallback path
// (count > CAP, never for uniform data) scatters via global gfill atomics.
__global__ __launch_bounds__(256) void sort_bucket(
    const int* __restrict__ row_start, const int2* __restrict__ temp,
    int* __restrict__ gfill, int2* __restrict__ colval) {
    __shared__ int2 stage[CAP];                      // 40 KB
    __shared__ int lstart[RPB2 + 1];
    __shared__ int lfill[RPB2];
    int b = blockIdx.x;
    int row0 = b * RPB2;
    int rcount = NN - row0; if (rcount > RPB2) rcount = RPB2;
    int tid = threadIdx.x;
    int s = row_start[row0];
    for (int r = tid; r <= rcount; r += 256) lstart[r] = row_start[row0 + r] - s;
    for (int r = tid; r < rcount; r += 256) lfill[r] = 0;
    __syncthreads();
    int count = lstart[rcount];
    if (count <= CAP) {
        for (int i = tid; i < count; i += 256) {
            int2 e = temp[s + i];
            int rl = e.x >> 19;
            int pos = lstart[rl] + atomicAdd(&lfill[rl], 1);
            stage[pos] = make_int2(e.x & 0x7FFFF, e.y);
        }
        __syncthreads();
        for (int i = tid; i < count; i += 256) colval[s + i] = stage[i];
    } else {
        for (int i = tid; i < count; i += 256) {
            int2 e = temp[s + i];
            int rl = e.x >> 19;
            int pos = atomicAdd(&gfill[row0 + rl], 1);
            colval[pos] = make_int2(e.x & 0x7FFFF, e.y);
        }
    }
}

// ---------------------------------------------------------------------------
// Atomic-free SpMM: one 32-lane half-wave per row (lane = feature d).
// Unroll-8: 8 independent 128B gathers in flight per half-wave.
// Fused y store + acc += y (and *0.25 on the last layer).
template <bool LAST>
__global__ __launch_bounds__(256) void spmm_csr(
    const int* __restrict__ row_start, const int2* __restrict__ colval,
    const float* __restrict__ x, float* __restrict__ y,
    float* __restrict__ acc) {
    int lane = threadIdx.x & 31;
    int row = blockIdx.x * 8 + (threadIdx.x >> 5);
    if (row >= NN) return;
    int s = row_start[row];
    int e = row_start[row + 1];
    float s0 = 0.f, s1 = 0.f, s2 = 0.f, s3 = 0.f;
    float s4 = 0.f, s5 = 0.f, s6 = 0.f, s7 = 0.f;
    int i = s;
    for (; i + 7 < e; i += 8) {
        int2 a0 = colval[i];
        int2 a1 = colval[i + 1];
        int2 a2 = colval[i + 2];
        int2 a3 = colval[i + 3];
        int2 a4 = colval[i + 4];
        int2 a5 = colval[i + 5];
        int2 a6 = colval[i + 6];
        int2 a7 = colval[i + 7];
        s0 += __int_as_float(a0.y) * x[a0.x * D + lane];
        s1 += __int_as_float(a1.y) * x[a1.x * D + lane];
        s2 += __int_as_float(a2.y) * x[a2.x * D + lane];
        s3 += __int_as_float(a3.y) * x[a3.x * D + lane];
        s4 += __int_as_float(a4.y) * x[a4.x * D + lane];
        s5 += __int_as_float(a5.y) * x[a5.x * D + lane];
        s6 += __int_as_float(a6.y) * x[a6.x * D + lane];
        s7 += __int_as_float(a7.y) * x[a7.x * D + lane];
    }
    for (; i < e; ++i) {
        int2 a = colval[i];
        s0 += __int_as_float(a.y) * x[a.x * D + lane];
    }
    float sum = ((s0 + s1) + (s2 + s3)) + ((s4 + s5) + (s6 + s7));
    int idx = row * D + lane;
    y[idx] = sum;
    float a = acc[idx] + sum;
    acc[idx] = LAST ? a * 0.25f : a;
}

extern "C" void kernel_launch(void* const* d_in, const int* in_sizes, int n_in,
                              void* d_out, int out_size, void* d_ws, size_t ws_size,
                              hipStream_t stream) {
    const int*   rows   = (const int*)d_in[0];
    const int*   cols   = (const int*)d_in[1];
    const float* vals   = (const float*)d_in[2];
    const float* user_w = (const float*)d_in[3];
    const float* item_w = (const float*)d_in[4];

    float* acc = (float*)d_out;

    // ws: x (38.4MB) | y (38.4MB) | colval (76.8MB) | counts | row_start | gfill | bfill
    // temp (76.8MB) aliases x|y — build runs before init_x_acc.
    float* x = (float*)d_ws;
    float* y = x + (size_t)TOTAL;
    int2*  temp = (int2*)d_ws;
    int2*  colval = (int2*)(y + (size_t)TOTAL);
    int*   counts = (int*)(colval + (size_t)NE);
    int*   row_start = counts + NN;
    int*   gfill = row_start + (NN + 1);
    int*   bfill = gfill + NN;

    const int vec_blocks  = (TOTAL / 4 + 255) / 256;   // 9375
    const int hist_blocks = (NE / 4 + 255) / 256;      // 9375
    const int partA_blocks = (NE + EPB_A - 1) / EPB_A; // 586
    const int row_blocks  = (NN + 7) / 8;              // 37500

    // Build exact CSR
    hipMemsetAsync(counts, 0, (size_t)NN * sizeof(int), stream);
    hist_kernel<<<hist_blocks, 256, 0, stream>>>((const int4*)rows, counts);
    scan_kernel<<<1, 1024, 0, stream>>>(counts, row_start, gfill);
    bucket_starts<<<(B2 + 255) / 256, 256, 0, stream>>>(row_start, bfill);
    partition_edges<<<partA_blocks, TPB_A, 0, stream>>>(
        (const int4*)rows, (const int4*)cols, (const float4*)vals, bfill, temp);
    sort_bucket<<<B2, 256, 0, stream>>>(row_start, temp, gfill, colval);

    // Embeddings + accumulator (after build: temp aliases x|y)
    init_x_acc<<<vec_blocks, 256, 0, stream>>>(
        (const float4*)user_w, (const float4*)item_w, (float4*)x, (float4*)acc);

    // 3 propagation layers, atomic-free
    spmm_csr<false><<<row_blocks, 256, 0, stream>>>(row_start, colval, x, y, acc);
    spmm_csr<false><<<row_blocks, 256, 0, stream>>>(row_start, colval, y, x, acc);
    spmm_csr<true ><<<row_blocks, 256, 0, stream>>>(row_start, colval, x, y, acc);
}

// Round 6
// 1328.026 us; speedup vs baseline: 5.4426x; 1.4914x over previous
//
#include <hip/hip_runtime.h>

#define NUM_USERS 200000
#define NUM_ITEMS 100000
#define NN (NUM_USERS + NUM_ITEMS)   // 300000
#define D 32
#define NE 9600000
#define TOTAL (NN * D)               // 9,600,000 floats

#define RPB2 128                     // rows per fine bucket
#define B2 ((NN + RPB2 - 1) / RPB2)  // 2344 buckets; region == CSR slice of 128 rows
#define CAP 5120                     // LDS stage capacity (mean 4096, sigma ~64)

#define TPB_A 1024                   // partition block size
#define EPT 16                       // edges per thread in partition
#define EPB_A (TPB_A * EPT)          // 16384 edges per block

#define SCAN_B 256                   // scan block threads (1024 counters/block)
#define NB_S ((NN + 1023) / 1024)    // 293 scan blocks

// ---------------------------------------------------------------------------
// init: x0 = concat(user_w, item_w); acc = x0. Runs AFTER the CSR build
// because the build's temp array aliases the x|y workspace.
__global__ __launch_bounds__(256) void init_x_acc(
    const float4* __restrict__ user_w, const float4* __restrict__ item_w,
    float4* __restrict__ x, float4* __restrict__ acc) {
    int i = blockIdx.x * 256 + threadIdx.x;
    const int total4 = TOTAL / 4;
    const int ub4 = (NUM_USERS * D) / 4;
    if (i < total4) {
        float4 v = (i < ub4) ? user_w[i] : item_w[i - ub4];
        x[i] = v;
        acc[i] = v;
    }
}

// ---------------------------------------------------------------------------
// Degree histogram, int4-vectorized (counts pre-zeroed).
__global__ __launch_bounds__(256) void hist_kernel(
    const int4* __restrict__ rows4, int* __restrict__ counts) {
    int t = blockIdx.x * 256 + threadIdx.x;
    if (t < NE / 4) {
        int4 r = rows4[t];
        atomicAdd(&counts[r.x], 1);
        atomicAdd(&counts[r.y], 1);
        atomicAdd(&counts[r.z], 1);
        atomicAdd(&counts[r.w], 1);
    }
}

// ---------------------------------------------------------------------------
// Device-wide exclusive scan, pass 1: per-block (1024 counters) tree-reduce.
__global__ __launch_bounds__(SCAN_B) void scan_block_reduce(
    const int4* __restrict__ counts4, int* __restrict__ bsums) {
    __shared__ int lds[SCAN_B];
    int t = threadIdx.x;
    int i4 = blockIdx.x * SCAN_B + t;                // int4 index
    int s = 0;
    if (i4 < NN / 4) {
        int4 c = counts4[i4];
        s = c.x + c.y + c.z + c.w;
    }
    lds[t] = s;
    __syncthreads();
    for (int off = SCAN_B / 2; off > 0; off >>= 1) {
        if (t < off) lds[t] += lds[t + off];
        __syncthreads();
    }
    if (t == 0) bsums[blockIdx.x] = lds[0];
}

// ---------------------------------------------------------------------------
// Pass 2: scan the 293 block sums in-place (-> exclusive offsets);
// writes row_start[NN] = NE.
__global__ __launch_bounds__(512) void scan_bsums(
    int* __restrict__ bsums, int* __restrict__ row_start) {
    __shared__ int lds[512];
    int t = threadIdx.x;
    int v = (t < NB_S) ? bsums[t] : 0;
    lds[t] = v;
    __syncthreads();
    for (int off = 1; off < 512; off <<= 1) {
        int u = (t >= off) ? lds[t - off] : 0;
        __syncthreads();
        lds[t] += u;
        __syncthreads();
    }
    if (t < NB_S) bsums[t] = lds[t] - v;             // exclusive
    if (t == 511) row_start[NN] = lds[511];          // == NE
}

// ---------------------------------------------------------------------------
// Pass 3: re-load counts, local LDS scan + block offset, emit row_start and
// gfill as int4 (both 16B-aligned by workspace padding).
__global__ __launch_bounds__(SCAN_B) void scan_expand(
    const int4* __restrict__ counts4, const int* __restrict__ bsums,
    int* __restrict__ row_start, int* __restrict__ gfill) {
    __shared__ int lds[SCAN_B];
    int t = threadIdx.x;
    int i4 = blockIdx.x * SCAN_B + t;
    int4 c = make_int4(0, 0, 0, 0);
    if (i4 < NN / 4) c = counts4[i4];
    int tot = c.x + c.y + c.z + c.w;
    lds[t] = tot;
    __syncthreads();
    for (int off = 1; off < SCAN_B; off <<= 1) {
        int u = (t >= off) ? lds[t - off] : 0;
        __syncthreads();
        lds[t] += u;
        __syncthreads();
    }
    int ex = bsums[blockIdx.x] + lds[t] - tot;       // exclusive prefix
    if (i4 < NN / 4) {
        int4 o;
        o.x = ex;
        o.y = o.x + c.x;
        o.z = o.y + c.y;
        o.w = o.z + c.z;
        ((int4*)row_start)[i4] = o;
        ((int4*)gfill)[i4] = o;
    }
}

// ---------------------------------------------------------------------------
// Bucket fill counters: bfill[b] = row_start[b*128] (bucket region start).
__global__ __launch_bounds__(256) void bucket_starts(
    const int* __restrict__ row_start, int* __restrict__ bfill) {
    int b = blockIdx.x * 256 + threadIdx.x;
    if (b < B2) bfill[b] = row_start[b * RPB2];
}

// ---------------------------------------------------------------------------
// Pass A: block-privatized counting-split of edges into the 2344 bucket
// regions of temp. Per block: LDS histogram -> per-edge rank; one global
// atomicAdd per touched bucket reserves a contiguous run; phase-2 reload
// writes (row_local<<19|col, val) at base+rank — dense ~56B runs per CU.
__global__ __launch_bounds__(TPB_A) void partition_edges(
    const int4* __restrict__ rows4, const int4* __restrict__ cols4,
    const float4* __restrict__ vals4, int* __restrict__ bfill,
    int2* __restrict__ temp) {
    __shared__ int hist[B2];                         // 9376 B
    int tid = threadIdx.x;
    for (int i = tid; i < B2; i += TPB_A) hist[i] = 0;
    __syncthreads();

    int base4 = blockIdx.x * (EPB_A / 4);
    int brank[EPT];                                  // (bucket<<16)|rank per edge

    #pragma unroll
    for (int k = 0; k < EPT / 4; ++k) {
        int i4 = base4 + k * TPB_A + tid;
        if (i4 < NE / 4) {
            int4 r = rows4[i4];
            int b0 = r.x >> 7, b1 = r.y >> 7, b2 = r.z >> 7, b3 = r.w >> 7;
            brank[k * 4 + 0] = (b0 << 16) | atomicAdd(&hist[b0], 1);
            brank[k * 4 + 1] = (b1 << 16) | atomicAdd(&hist[b1], 1);
            brank[k * 4 + 2] = (b2 << 16) | atomicAdd(&hist[b2], 1);
            brank[k * 4 + 3] = (b3 << 16) | atomicAdd(&hist[b3], 1);
        }
    }
    __syncthreads();
    for (int b = tid; b < B2; b += TPB_A) {          // reserve runs
        int c = hist[b];
        if (c) hist[b] = atomicAdd(&bfill[b], c);    // hist now holds base
    }
    __syncthreads();

    #pragma unroll
    for (int k = 0; k < EPT / 4; ++k) {
        int i4 = base4 + k * TPB_A + tid;
        if (i4 < NE / 4) {
            int4 r = rows4[i4];
            int4 c = cols4[i4];
            float4 v = vals4[i4];
            int br, pos; int2 cv;
            br = brank[k * 4 + 0]; pos = hist[br >> 16] + (br & 0xFFFF);
            cv.x = ((r.x & 127) << 19) | c.x; cv.y = __float_as_int(v.x); temp[pos] = cv;
            br = brank[k * 4 + 1]; pos = hist[br >> 16] + (br & 0xFFFF);
            cv.x = ((r.y & 127) << 19) | c.y; cv.y = __float_as_int(v.y); temp[pos] = cv;
            br = brank[k * 4 + 2]; pos = hist[br >> 16] + (br & 0xFFFF);
            cv.x = ((r.z & 127) << 19) | c.z; cv.y = __float_as_int(v.z); temp[pos] = cv;
            br = brank[k * 4 + 3]; pos = hist[br >> 16] + (br & 0xFFFF);
            cv.x = ((r.w & 127) << 19) | c.w; cv.y = __float_as_int(v.w); temp[pos] = cv;
        }
    }
}

// ---------------------------------------------------------------------------
// Pass B: exact within-bucket counting sort through LDS. One block per
// bucket: contiguous read of temp region, LDS int-atomic ranks, staged
// (col,val) in LDS, fully-coalesced flush to final colval. Fallback path
// (count > CAP, never for uniform data) scatters via global gfill atomics.
__global__ __launch_bounds__(256) void sort_bucket(
    const int* __restrict__ row_start, const int2* __restrict__ temp,
    int* __restrict__ gfill, int2* __restrict__ colval) {
    __shared__ int2 stage[CAP];                      // 40 KB
    __shared__ int lstart[RPB2 + 1];
    __shared__ int lfill[RPB2];
    int b = blockIdx.x;
    int row0 = b * RPB2;
    int rcount = NN - row0; if (rcount > RPB2) rcount = RPB2;
    int tid = threadIdx.x;
    int s = row_start[row0];
    for (int r = tid; r <= rcount; r += 256) lstart[r] = row_start[row0 + r] - s;
    for (int r = tid; r < rcount; r += 256) lfill[r] = 0;
    __syncthreads();
    int count = lstart[rcount];
    if (count <= CAP) {
        for (int i = tid; i < count; i += 256) {
            int2 e = temp[s + i];
            int rl = e.x >> 19;
            int pos = lstart[rl] + atomicAdd(&lfill[rl], 1);
            stage[pos] = make_int2(e.x & 0x7FFFF, e.y);
        }
        __syncthreads();
        for (int i = tid; i < count; i += 256) colval[s + i] = stage[i];
    } else {
        for (int i = tid; i < count; i += 256) {
            int2 e = temp[s + i];
            int rl = e.x >> 19;
            int pos = atomicAdd(&gfill[row0 + rl], 1);
            colval[pos] = make_int2(e.x & 0x7FFFF, e.y);
        }
    }
}

// ---------------------------------------------------------------------------
// Atomic-free SpMM: one 32-lane half-wave per row (lane = feature d).
// Unroll-8: 8 independent 128B gathers in flight per half-wave.
// Fused y store + acc += y (and *0.25 on the last layer).
template <bool LAST>
__global__ __launch_bounds__(256) void spmm_csr(
    const int* __restrict__ row_start, const int2* __restrict__ colval,
    const float* __restrict__ x, float* __restrict__ y,
    float* __restrict__ acc) {
    int lane = threadIdx.x & 31;
    int row = blockIdx.x * 8 + (threadIdx.x >> 5);
    if (row >= NN) return;
    int s = row_start[row];
    int e = row_start[row + 1];
    float s0 = 0.f, s1 = 0.f, s2 = 0.f, s3 = 0.f;
    float s4 = 0.f, s5 = 0.f, s6 = 0.f, s7 = 0.f;
    int i = s;
    for (; i + 7 < e; i += 8) {
        int2 a0 = colval[i];
        int2 a1 = colval[i + 1];
        int2 a2 = colval[i + 2];
        int2 a3 = colval[i + 3];
        int2 a4 = colval[i + 4];
        int2 a5 = colval[i + 5];
        int2 a6 = colval[i + 6];
        int2 a7 = colval[i + 7];
        s0 += __int_as_float(a0.y) * x[a0.x * D + lane];
        s1 += __int_as_float(a1.y) * x[a1.x * D + lane];
        s2 += __int_as_float(a2.y) * x[a2.x * D + lane];
        s3 += __int_as_float(a3.y) * x[a3.x * D + lane];
        s4 += __int_as_float(a4.y) * x[a4.x * D + lane];
        s5 += __int_as_float(a5.y) * x[a5.x * D + lane];
        s6 += __int_as_float(a6.y) * x[a6.x * D + lane];
        s7 += __int_as_float(a7.y) * x[a7.x * D + lane];
    }
    for (; i < e; ++i) {
        int2 a = colval[i];
        s0 += __int_as_float(a.y) * x[a.x * D + lane];
    }
    float sum = ((s0 + s1) + (s2 + s3)) + ((s4 + s5) + (s6 + s7));
    int idx = row * D + lane;
    y[idx] = sum;
    float a = acc[idx] + sum;
    acc[idx] = LAST ? a * 0.25f : a;
}

extern "C" void kernel_launch(void* const* d_in, const int* in_sizes, int n_in,
                              void* d_out, int out_size, void* d_ws, size_t ws_size,
                              hipStream_t stream) {
    const int*   rows   = (const int*)d_in[0];
    const int*   cols   = (const int*)d_in[1];
    const float* vals   = (const float*)d_in[2];
    const float* user_w = (const float*)d_in[3];
    const float* item_w = (const float*)d_in[4];

    float* acc = (float*)d_out;

    // ws layout (16B alignment maintained):
    //   x (38.4MB) | y (38.4MB) | colval (76.8MB) |
    //   counts[NN] | row_start[NN+4 pad] | gfill[NN] | bsums[NB_S] | bfill[B2]
    // temp (76.8MB) aliases x|y — build runs before init_x_acc.
    float* x = (float*)d_ws;
    float* y = x + (size_t)TOTAL;
    int2*  temp = (int2*)d_ws;
    int2*  colval = (int2*)(y + (size_t)TOTAL);
    int*   counts = (int*)(colval + (size_t)NE);
    int*   row_start = counts + NN;                  // NN+4 slots (padded)
    int*   gfill = row_start + (NN + 4);             // 16B-aligned
    int*   bsums = gfill + NN;
    int*   bfill = bsums + NB_S;

    const int vec_blocks  = (TOTAL / 4 + 255) / 256;   // 9375
    const int hist_blocks = (NE / 4 + 255) / 256;      // 9375
    const int partA_blocks = (NE + EPB_A - 1) / EPB_A; // 586
    const int row_blocks  = (NN + 7) / 8;              // 37500

    // Build exact CSR
    hipMemsetAsync(counts, 0, (size_t)NN * sizeof(int), stream);
    hist_kernel<<<hist_blocks, 256, 0, stream>>>((const int4*)rows, counts);
    scan_block_reduce<<<NB_S, SCAN_B, 0, stream>>>((const int4*)counts, bsums);
    scan_bsums<<<1, 512, 0, stream>>>(bsums, row_start);
    scan_expand<<<NB_S, SCAN_B, 0, stream>>>(
        (const int4*)counts, bsums, row_start, gfill);
    bucket_starts<<<(B2 + 255) / 256, 256, 0, stream>>>(row_start, bfill);
    partition_edges<<<partA_blocks, TPB_A, 0, stream>>>(
        (const int4*)rows, (const int4*)cols, (const float4*)vals, bfill, temp);
    sort_bucket<<<B2, 256, 0, stream>>>(row_start, temp, gfill, colval);

    // Embeddings + accumulator (after build: temp aliases x|y)
    init_x_acc<<<vec_blocks, 256, 0, stream>>>(
        (const float4*)user_w, (const float4*)item_w, (float4*)x, (float4*)acc);

    // 3 propagation layers, atomic-free
    spmm_csr<false><<<row_blocks, 256, 0, stream>>>(row_start, colval, x, y, acc);
    spmm_csr<false><<<row_blocks, 256, 0, stream>>>(row_start, colval, y, x, acc);
    spmm_csr<true ><<<row_blocks, 256, 0, stream>>>(row_start, colval, x, y, acc);
}